// Round 4
// baseline (907.904 us; speedup 1.0000x reference)
//
#include <hip/hip_runtime.h>
#include <hip/hip_bf16.h>

// Problem constants
#define B_SZ 2
#define LSEQ 1024
#define DIN  2048
#define DST  16
#define DTR  64
#define KTOT 96              // DTR + 2*DST
#define NROW (B_SZ * LSEQ)   // 2048 (b,l) rows
#define NCH  64              // number of L-chunks
#define TCH  16              // timesteps per chunk (LSEQ / NCH)
#define KSP  32              // K-splits in k_proj (64 K each)

// bf16 (as ushort) -> float
__device__ __forceinline__ float b2f(unsigned int u) {
    union { unsigned int i; float f; } v;
    v.i = (u & 0xffffu) << 16;
    return v.f;
}

// scalar load: element i of a buffer that is either fp32 or bf16
__device__ __forceinline__ float ldf(const void* p, size_t i, bool f32) {
    return f32 ? ((const float*)p)[i] : b2f(((const unsigned short*)p)[i]);
}

// 4 consecutive elements as float4, dual dtype
__device__ __forceinline__ float4 ld4(const void* p, size_t i, bool f32) {
    if (f32) return *(const float4*)((const float*)p + i);
    const uint2 u = *(const uint2*)((const unsigned short*)p + i);
    float4 v;
    v.x = b2f(u.x); v.y = b2f(u.x >> 16);
    v.z = b2f(u.y); v.w = b2f(u.y >> 16);
    return v;
}

__device__ __forceinline__ float softplus_f(float v) {
    return (v > 20.f) ? v : log1pf(__expf(v));
}

// Shared prologue for the scan kernels: compute this thread's TCH dt values
//   dt[t] = softplus(drw_row(t) . Wdt[d] + bdt[d])
// drL is the block's staged drw rows, flat [TCH*DTR], wave-uniform reads.
__device__ __forceinline__ void compute_dt16(
    const float* __restrict__ drL, const void* __restrict__ Wdt,
    const void* __restrict__ bdt, int d, bool f32, float* dtv)
{
    const float bd = ldf(bdt, (size_t)d, f32);
    #pragma unroll
    for (int t = 0; t < TCH; t++) dtv[t] = bd;
    #pragma unroll
    for (int kq = 0; kq < DTR / 4; kq++) {
        const float4 w = ld4(Wdt, (size_t)d * DTR + kq * 4, f32);
        #pragma unroll
        for (int t = 0; t < TCH; t++) {
            const float4 dr = *(const float4*)(drL + t * DTR + kq * 4);
            dtv[t] += w.x * dr.x + w.y * dr.y + w.z * dr.z + w.w * dr.w;
        }
    }
    #pragma unroll
    for (int t = 0; t < TCH; t++) dtv[t] = softplus_f(dtv[t]);
}

// ---------------------------------------------------------------------------
// Kernel 0: dtype detector. flag=1 -> fp32, flag=0 -> bf16.
// ---------------------------------------------------------------------------
__global__ __launch_bounds__(256) void k_detect(const void* __restrict__ x,
                                                int* __restrict__ flag) {
    __shared__ int cnt;
    if (threadIdx.x == 0) cnt = 0;
    __syncthreads();
    const unsigned short* u = (const unsigned short*)x;
    int my = 0;
    for (int i = threadIdx.x; i < 4096; i += 256) {
        unsigned short v = u[2 * i];
        float af = fabsf(b2f(v));
        if (v == 0 || (af >= 6.0e-8f && af <= 1.7e7f)) my++;
    }
    atomicAdd(&cnt, my);
    __syncthreads();
    if (threadIdx.x == 0) *flag = (cnt < 2048) ? 1 : 0;
}

// ---------------------------------------------------------------------------
// Kernel 1: input projection, tiled split-K GEMM.
// C[2048][96] = x[2048][2048] . Wx^T. Tile 64 rows x 96 cols x 64 K,
// 192 threads, thread-tile 4x8. Partials to part[ksplit][row][96].
// ---------------------------------------------------------------------------
__global__ __launch_bounds__(192) void k_proj(
    const void* __restrict__ x,      // [NROW][DIN]
    const void* __restrict__ Wx,     // [96][DIN]
    const int*  __restrict__ flag,
    float* __restrict__ part)        // [KSP][NROW][96]
{
    const bool f32 = (*flag != 0);
    __shared__ float lx[32][68];     // [k][row], padded
    __shared__ float lw[32][100];    // [k][col], padded
    const int tid = threadIdx.x;
    const int bx = blockIdx.x;       // row group (64 rows)
    const int by = blockIdx.y;       // K-split (64 K)
    const int rt = tid / 12, ct = tid % 12;
    const int r0 = rt * 4, c0 = ct * 8;

    float acc[4][8];
    #pragma unroll
    for (int i = 0; i < 4; i++)
        #pragma unroll
        for (int k = 0; k < 8; k++) acc[i][k] = 0.f;

    for (int half = 0; half < 2; half++) {
        const int k0 = by * 64 + half * 32;
        // stage x tile: 64 rows x 32 k (K-major in LDS)
        for (int idx = tid; idx < 512; idx += 192) {
            const int r = idx >> 3, q = idx & 7;
            float4 v = ld4(x, (size_t)(bx * 64 + r) * DIN + k0 + q * 4, f32);
            lx[q * 4 + 0][r] = v.x; lx[q * 4 + 1][r] = v.y;
            lx[q * 4 + 2][r] = v.z; lx[q * 4 + 3][r] = v.w;
        }
        // stage w tile: 96 cols x 32 k
        for (int idx = tid; idx < 768; idx += 192) {
            const int c = idx >> 3, q = idx & 7;
            float4 v = ld4(Wx, (size_t)c * DIN + k0 + q * 4, f32);
            lw[q * 4 + 0][c] = v.x; lw[q * 4 + 1][c] = v.y;
            lw[q * 4 + 2][c] = v.z; lw[q * 4 + 3][c] = v.w;
        }
        __syncthreads();

        for (int j = 0; j < 32; j++) {
            const float4 xa = *(const float4*)&lx[j][r0];
            const float4 wa = *(const float4*)&lw[j][c0];
            const float4 wb = *(const float4*)&lw[j][c0 + 4];
            const float xr[4] = {xa.x, xa.y, xa.z, xa.w};
            const float wc[8] = {wa.x, wa.y, wa.z, wa.w, wb.x, wb.y, wb.z, wb.w};
            #pragma unroll
            for (int i = 0; i < 4; i++)
                #pragma unroll
                for (int k = 0; k < 8; k++)
                    acc[i][k] += xr[i] * wc[k];
        }
        __syncthreads();
    }

    float* p = part + (size_t)by * NROW * KTOT + (size_t)(bx * 64) * KTOT;
    #pragma unroll
    for (int i = 0; i < 4; i++) {
        float* row = p + (size_t)(r0 + i) * KTOT + c0;
        *(float4*)(row)     = make_float4(acc[i][0], acc[i][1], acc[i][2], acc[i][3]);
        *(float4*)(row + 4) = make_float4(acc[i][4], acc[i][5], acc[i][6], acc[i][7]);
    }
}

// ---------------------------------------------------------------------------
// Kernel 2: combine K-split partials -> drw / Bin / Cin.
// ---------------------------------------------------------------------------
__global__ __launch_bounds__(256) void k_comb(
    const float* __restrict__ part,
    float* __restrict__ drw, float* __restrict__ Bin, float* __restrict__ Cin)
{
    const int idx = blockIdx.x * 256 + threadIdx.x;   // < NROW*96
    float s = 0.f;
    #pragma unroll 8
    for (int ks = 0; ks < KSP; ks++)
        s += part[(size_t)ks * NROW * KTOT + idx];
    const int r = idx / KTOT, c = idx % KTOT;
    if (c < DTR)            drw[r * DTR + c] = s;
    else if (c < DTR + DST) Bin[r * DST + (c - DTR)] = s;
    else                    Cin[r * DST + (c - DTR - DST)] = s;
}

// ---------------------------------------------------------------------------
// Kernel 3 (scan phase 1): per (b, chunk, d): compute dt in-register (fused
// dt-GEMM), then chunk-local scan with h0=0:
//   P[s] = prod_t exp(dt*A[s]),  H[s] = end state.
// ---------------------------------------------------------------------------
__global__ __launch_bounds__(256) void k_scan1(
    const void* __restrict__ x,
    const void* __restrict__ Wdt,
    const void* __restrict__ bdt,
    const void* __restrict__ Alog,
    const float* __restrict__ drw,
    const float* __restrict__ Bin,
    const int*  __restrict__ flag,
    float* __restrict__ Pb,          // [B][NCH][DST][DIN]
    float* __restrict__ Hb)
{
    const bool f32 = (*flag != 0);
    __shared__ float drL[TCH * DTR];   // 4 KB
    __shared__ float Bs[TCH * DST];    // 1 KB
    const int tid = threadIdx.x;
    const int d = blockIdx.x * 256 + tid;
    const int c = blockIdx.y;
    const int b = blockIdx.z;
    const int row0 = b * LSEQ + c * TCH;

    // stage drw rows (contiguous TCH*DTR floats) + Bin rows
    {
        float4 v = *(const float4*)(drw + (size_t)row0 * DTR + tid * 4);
        *(float4*)(drL + tid * 4) = v;
        if (tid < TCH * DST) Bs[tid] = Bin[(size_t)row0 * DST + tid];
    }

    float A[DST];
    #pragma unroll
    for (int sq = 0; sq < DST / 4; sq++) {
        float4 av = ld4(Alog, (size_t)d * DST + sq * 4, f32);
        A[sq * 4 + 0] = -__expf(av.x); A[sq * 4 + 1] = -__expf(av.y);
        A[sq * 4 + 2] = -__expf(av.z); A[sq * 4 + 3] = -__expf(av.w);
    }
    // prefetch x column for this chunk
    float xv[TCH];
    #pragma unroll
    for (int t = 0; t < TCH; t++)
        xv[t] = ldf(x, (size_t)(row0 + t) * DIN + d, f32);
    __syncthreads();

    float dtv[TCH];
    compute_dt16(drL, Wdt, bdt, d, f32, dtv);

    float P[DST], H[DST];
    #pragma unroll
    for (int s = 0; s < DST; s++) { P[s] = 1.f; H[s] = 0.f; }

    #pragma unroll
    for (int t = 0; t < TCH; t++) {
        const float u = dtv[t] * xv[t];
        const float* bs = Bs + t * DST;
        #pragma unroll
        for (int s = 0; s < DST; s++) {
            const float e = __expf(dtv[t] * A[s]);
            P[s] *= e;
            H[s] = e * H[s] + u * bs[s];
        }
    }

    const size_t base = (size_t)(b * NCH + c) * DST * DIN + d;
    #pragma unroll
    for (int s = 0; s < DST; s++) {
        Pb[base + (size_t)s * DIN] = P[s];
        Hb[base + (size_t)s * DIN] = H[s];
    }
}

// ---------------------------------------------------------------------------
// Kernel 4 (scan phase 2): cross-chunk exclusive scan per (b,s,d).
// IN-PLACE: Pb becomes hin[c] (state entering chunk c).
// ---------------------------------------------------------------------------
__global__ __launch_bounds__(256) void k_scan2(
    float* __restrict__ Pb,
    const float* __restrict__ Hb)
{
    const int idx = blockIdx.x * 256 + threadIdx.x;
    const int b   = idx / (DST * DIN);
    const int rem = idx % (DST * DIN);
    float h = 0.f;
    #pragma unroll 4
    for (int c = 0; c < NCH; c++) {
        const size_t o = (size_t)(b * NCH + c) * DST * DIN + rem;
        const float p = Pb[o], hb = Hb[o];
        Pb[o] = h;
        h = hb + p * h;
    }
}

// ---------------------------------------------------------------------------
// Kernel 5 (scan phase 3): recompute dt, local scan seeded with hin, emit y.
// ---------------------------------------------------------------------------
__global__ __launch_bounds__(256) void k_scan3(
    const void* __restrict__ x,
    const void* __restrict__ Wdt,
    const void* __restrict__ bdt,
    const void* __restrict__ Alog,
    const void* __restrict__ Dv,
    const float* __restrict__ drw,
    const float* __restrict__ Bin,
    const float* __restrict__ Cin,
    const float* __restrict__ hin,   // = Pb after k_scan2
    const int*  __restrict__ flag,
    void* __restrict__ y)
{
    const bool f32 = (*flag != 0);
    __shared__ float drL[TCH * DTR];
    __shared__ float Bs[TCH * DST];
    __shared__ float Cs[TCH * DST];
    const int tid = threadIdx.x;
    const int d = blockIdx.x * 256 + tid;
    const int c = blockIdx.y;
    const int b = blockIdx.z;
    const int row0 = b * LSEQ + c * TCH;

    {
        float4 v = *(const float4*)(drw + (size_t)row0 * DTR + tid * 4);
        *(float4*)(drL + tid * 4) = v;
        if (tid < TCH * DST) {
            Bs[tid] = Bin[(size_t)row0 * DST + tid];
            Cs[tid] = Cin[(size_t)row0 * DST + tid];
        }
    }

    float A[DST];
    #pragma unroll
    for (int sq = 0; sq < DST / 4; sq++) {
        float4 av = ld4(Alog, (size_t)d * DST + sq * 4, f32);
        A[sq * 4 + 0] = -__expf(av.x); A[sq * 4 + 1] = -__expf(av.y);
        A[sq * 4 + 2] = -__expf(av.z); A[sq * 4 + 3] = -__expf(av.w);
    }
    const float Dd = ldf(Dv, (size_t)d, f32);
    float xv[TCH];
    #pragma unroll
    for (int t = 0; t < TCH; t++)
        xv[t] = ldf(x, (size_t)(row0 + t) * DIN + d, f32);
    __syncthreads();

    float dtv[TCH];
    compute_dt16(drL, Wdt, bdt, d, f32, dtv);

    float h[DST];
    const size_t base = (size_t)(b * NCH + c) * DST * DIN + d;
    #pragma unroll
    for (int s = 0; s < DST; s++) h[s] = hin[base + (size_t)s * DIN];

    #pragma unroll
    for (int t = 0; t < TCH; t++) {
        const float u = dtv[t] * xv[t];
        const float* bs = Bs + t * DST;
        const float* cs = Cs + t * DST;
        float yv = Dd * xv[t];
        #pragma unroll
        for (int s = 0; s < DST; s++) {
            const float e = __expf(dtv[t] * A[s]);
            h[s] = e * h[s] + u * bs[s];
            yv += h[s] * cs[s];
        }
        const size_t off = (size_t)(row0 + t) * DIN + d;
        if (f32) ((float*)y)[off] = yv;
        else     ((__hip_bfloat16*)y)[off] = __float2bfloat16(yv);
    }
}

// ---------------------------------------------------------------------------
extern "C" void kernel_launch(void* const* d_in, const int* in_sizes, int n_in,
                              void* d_out, int out_size, void* d_ws, size_t ws_size,
                              hipStream_t stream) {
    const void* x    = d_in[0];
    const void* Wx   = d_in[1];
    const void* Wdt  = d_in[2];
    const void* bdt  = d_in[3];
    const void* Alog = d_in[4];
    const void* Dv   = d_in[5];

    // ---- workspace layout (~34.4 MB) ----
    // [flag | drw | Bin | Cin | big]
    //   big phase A: part (KSP*NROW*96 = 6.29M floats)
    //   big phase B: Pb (4.19M) + Hb (4.19M)       (part dead after k_comb)
    int*   flag  = (int*)d_ws;
    float* basep = (float*)d_ws + 16;
    float* drw   = basep;                                  // NROW*DTR
    float* Bin   = drw + (size_t)NROW * DTR;               // NROW*DST
    float* Cin   = Bin + (size_t)NROW * DST;               // NROW*DST
    float* big   = Cin + (size_t)NROW * DST;
    float* part  = big;                                    // 6,291,456 floats
    float* Pb    = big;                                    // 4,194,304 floats
    float* Hb    = Pb + (size_t)B_SZ * NCH * DST * DIN;    // 4,194,304 floats

    k_detect<<<1, 256, 0, stream>>>(x, flag);

    k_proj<<<dim3(NROW / 64, KSP), 192, 0, stream>>>(x, Wx, flag, part);

    k_comb<<<(NROW * KTOT) / 256, 256, 0, stream>>>(part, drw, Bin, Cin);

    dim3 g1(DIN / 256, NCH, B_SZ);
    k_scan1<<<g1, 256, 0, stream>>>(x, Wdt, bdt, Alog, drw, Bin, flag, Pb, Hb);

    k_scan2<<<(B_SZ * DST * DIN) / 256, 256, 0, stream>>>(Pb, Hb);

    k_scan3<<<g1, 256, 0, stream>>>(x, Wdt, bdt, Alog, Dv, drw, Bin, Cin,
                                    Pb, flag, d_out);
}

// Round 5
// 232.550 us; speedup vs baseline: 3.9041x; 3.9041x over previous
//
#include <hip/hip_runtime.h>
#include <hip/hip_bf16.h>

// Problem constants
#define B_SZ 2
#define LSEQ 1024
#define DIN  2048
#define DST  16
#define DTR  64
#define KTOT 96              // DTR + 2*DST
#define NROW (B_SZ * LSEQ)   // 2048 (b,l) rows
#define NCH  64              // number of L-chunks
#define TCH  16              // timesteps per chunk (LSEQ / NCH)
#define KSP  32              // K-splits in k_proj (64 K each)

// bf16 (as ushort) -> float
__device__ __forceinline__ float b2f(unsigned int u) {
    union { unsigned int i; float f; } v;
    v.i = (u & 0xffffu) << 16;
    return v.f;
}

// scalar load: element i of a buffer that is either fp32 or bf16
__device__ __forceinline__ float ldf(const void* p, size_t i, bool f32) {
    return f32 ? ((const float*)p)[i] : b2f(((const unsigned short*)p)[i]);
}

// 4 consecutive elements as float4, dual dtype
__device__ __forceinline__ float4 ld4(const void* p, size_t i, bool f32) {
    if (f32) return *(const float4*)((const float*)p + i);
    const uint2 u = *(const uint2*)((const unsigned short*)p + i);
    float4 v;
    v.x = b2f(u.x); v.y = b2f(u.x >> 16);
    v.z = b2f(u.y); v.w = b2f(u.y >> 16);
    return v;
}

__device__ __forceinline__ float softplus_f(float v) {
    return (v > 20.f) ? v : log1pf(__expf(v));
}

// ---------------------------------------------------------------------------
// Kernel 0: dtype detector. flag=1 -> fp32, flag=0 -> bf16.
// ---------------------------------------------------------------------------
__global__ __launch_bounds__(256) void k_detect(const void* __restrict__ x,
                                                int* __restrict__ flag) {
    __shared__ int cnt;
    if (threadIdx.x == 0) cnt = 0;
    __syncthreads();
    const unsigned short* u = (const unsigned short*)x;
    int my = 0;
    for (int i = threadIdx.x; i < 4096; i += 256) {
        unsigned short v = u[2 * i];
        float af = fabsf(b2f(v));
        if (v == 0 || (af >= 6.0e-8f && af <= 1.7e7f)) my++;
    }
    atomicAdd(&cnt, my);
    __syncthreads();
    if (threadIdx.x == 0) *flag = (cnt < 2048) ? 1 : 0;
}

// ---------------------------------------------------------------------------
// Kernel 1: input projection, tiled split-K GEMM.
// C[2048][96] = x[2048][2048] . Wx^T. Tile 64 rows x 96 cols x 64 K,
// 192 threads, thread-tile 4x8. Partials to part[ksplit][row][96].
// ---------------------------------------------------------------------------
__global__ __launch_bounds__(192) void k_proj(
    const void* __restrict__ x,      // [NROW][DIN]
    const void* __restrict__ Wx,     // [96][DIN]
    const int*  __restrict__ flag,
    float* __restrict__ part)        // [KSP][NROW][96]
{
    const bool f32 = (*flag != 0);
    __shared__ float lx[32][68];     // [k][row], padded
    __shared__ float lw[32][100];    // [k][col], padded
    const int tid = threadIdx.x;
    const int bx = blockIdx.x;       // row group (64 rows)
    const int by = blockIdx.y;       // K-split (64 K)
    const int rt = tid / 12, ct = tid % 12;
    const int r0 = rt * 4, c0 = ct * 8;

    float acc[4][8];
    #pragma unroll
    for (int i = 0; i < 4; i++)
        #pragma unroll
        for (int k = 0; k < 8; k++) acc[i][k] = 0.f;

    for (int half = 0; half < 2; half++) {
        const int k0 = by * 64 + half * 32;
        for (int idx = tid; idx < 512; idx += 192) {
            const int r = idx >> 3, q = idx & 7;
            float4 v = ld4(x, (size_t)(bx * 64 + r) * DIN + k0 + q * 4, f32);
            lx[q * 4 + 0][r] = v.x; lx[q * 4 + 1][r] = v.y;
            lx[q * 4 + 2][r] = v.z; lx[q * 4 + 3][r] = v.w;
        }
        for (int idx = tid; idx < 768; idx += 192) {
            const int c = idx >> 3, q = idx & 7;
            float4 v = ld4(Wx, (size_t)c * DIN + k0 + q * 4, f32);
            lw[q * 4 + 0][c] = v.x; lw[q * 4 + 1][c] = v.y;
            lw[q * 4 + 2][c] = v.z; lw[q * 4 + 3][c] = v.w;
        }
        __syncthreads();

        for (int j = 0; j < 32; j++) {
            const float4 xa = *(const float4*)&lx[j][r0];
            const float4 wa = *(const float4*)&lw[j][c0];
            const float4 wb = *(const float4*)&lw[j][c0 + 4];
            const float xr[4] = {xa.x, xa.y, xa.z, xa.w};
            const float wc[8] = {wa.x, wa.y, wa.z, wa.w, wb.x, wb.y, wb.z, wb.w};
            #pragma unroll
            for (int i = 0; i < 4; i++)
                #pragma unroll
                for (int k = 0; k < 8; k++)
                    acc[i][k] += xr[i] * wc[k];
        }
        __syncthreads();
    }

    float* p = part + (size_t)by * NROW * KTOT + (size_t)(bx * 64) * KTOT;
    #pragma unroll
    for (int i = 0; i < 4; i++) {
        float* row = p + (size_t)(r0 + i) * KTOT + c0;
        *(float4*)(row)     = make_float4(acc[i][0], acc[i][1], acc[i][2], acc[i][3]);
        *(float4*)(row + 4) = make_float4(acc[i][4], acc[i][5], acc[i][6], acc[i][7]);
    }
}

// ---------------------------------------------------------------------------
// Kernel 2: combine K-split partials -> drw / Bin / Cin.
// ---------------------------------------------------------------------------
__global__ __launch_bounds__(256) void k_comb(
    const float* __restrict__ part,
    float* __restrict__ drw, float* __restrict__ Bin, float* __restrict__ Cin)
{
    const int idx = blockIdx.x * 256 + threadIdx.x;   // < NROW*96
    float s = 0.f;
    #pragma unroll 8
    for (int ks = 0; ks < KSP; ks++)
        s += part[(size_t)ks * NROW * KTOT + idx];
    const int r = idx / KTOT, c = idx % KTOT;
    if (c < DTR)            drw[r * DTR + c] = s;
    else if (c < DTR + DST) Bin[r * DST + (c - DTR)] = s;
    else                    Cin[r * DST + (c - DTR - DST)] = s;
}

// ---------------------------------------------------------------------------
// Kernel 3: dt GEMM + softplus.  dt[r][d] = softplus(drw[r] . Wdt[d] + bdt[d])
// M=2048, N=2048, K=64 (single LDS stage). Block 256, tile 64x64, thread 4x4.
// ---------------------------------------------------------------------------
__global__ __launch_bounds__(256) void k_dt(
    const float* __restrict__ drw,   // [NROW][DTR]
    const void* __restrict__ Wdt,    // [DIN][DTR]
    const void* __restrict__ bdt,    // [DIN]
    const int*  __restrict__ flag,
    float* __restrict__ dt)          // [NROW][DIN]
{
    const bool f32 = (*flag != 0);
    __shared__ float la[64][68];     // [k][row]
    __shared__ float lb[64][68];     // [k][col]
    const int tid = threadIdx.x;
    const int r0g = blockIdx.x * 64, c0g = blockIdx.y * 64;

    for (int idx = tid; idx < 1024; idx += 256) {
        const int r = idx >> 4, q = idx & 15;
        float4 v = *(const float4*)(drw + (size_t)(r0g + r) * DTR + q * 4);
        la[q * 4 + 0][r] = v.x; la[q * 4 + 1][r] = v.y;
        la[q * 4 + 2][r] = v.z; la[q * 4 + 3][r] = v.w;
    }
    for (int idx = tid; idx < 1024; idx += 256) {
        const int c = idx >> 4, q = idx & 15;
        float4 v = ld4(Wdt, (size_t)(c0g + c) * DTR + q * 4, f32);
        lb[q * 4 + 0][c] = v.x; lb[q * 4 + 1][c] = v.y;
        lb[q * 4 + 2][c] = v.z; lb[q * 4 + 3][c] = v.w;
    }
    __syncthreads();

    const int rt = tid >> 4, ct = tid & 15;
    const int r0 = rt * 4, c0 = ct * 4;
    float acc[4][4];
    #pragma unroll
    for (int i = 0; i < 4; i++)
        #pragma unroll
        for (int k = 0; k < 4; k++) acc[i][k] = 0.f;

    for (int j = 0; j < 64; j++) {
        const float4 a = *(const float4*)&la[j][r0];
        const float4 b = *(const float4*)&lb[j][c0];
        const float ar[4] = {a.x, a.y, a.z, a.w};
        const float bc[4] = {b.x, b.y, b.z, b.w};
        #pragma unroll
        for (int i = 0; i < 4; i++)
            #pragma unroll
            for (int k = 0; k < 4; k++)
                acc[i][k] += ar[i] * bc[k];
    }

    float bd[4];
    #pragma unroll
    for (int k = 0; k < 4; k++) bd[k] = ldf(bdt, (size_t)(c0g + c0 + k), f32);
    #pragma unroll
    for (int i = 0; i < 4; i++) {
        float4 o;
        o.x = softplus_f(acc[i][0] + bd[0]);
        o.y = softplus_f(acc[i][1] + bd[1]);
        o.z = softplus_f(acc[i][2] + bd[2]);
        o.w = softplus_f(acc[i][3] + bd[3]);
        *(float4*)(dt + (size_t)(r0g + r0 + i) * DIN + c0g + c0) = o;
    }
}

// ---------------------------------------------------------------------------
// Kernel 4 (scan phase 1): per (b, chunk, d) chunk-local scan, h0=0.
//   P[s] = prod_t exp(dt*A[s]),  H[s] = end state.
// ---------------------------------------------------------------------------
__global__ __launch_bounds__(256) void k_scan1(
    const void* __restrict__ x,
    const float* __restrict__ dt,
    const float* __restrict__ Bin,
    const void* __restrict__ Alog,
    const int*  __restrict__ flag,
    float* __restrict__ Pb,          // [B][NCH][DST][DIN]
    float* __restrict__ Hb)
{
    const bool f32 = (*flag != 0);
    __shared__ float Bs[TCH * DST];
    const int tid = threadIdx.x;
    const int d = blockIdx.x * 256 + tid;
    const int c = blockIdx.y;
    const int b = blockIdx.z;
    const int row0 = b * LSEQ + c * TCH;

    if (tid < TCH * DST) Bs[tid] = Bin[(size_t)row0 * DST + tid];

    float A[DST];
    #pragma unroll
    for (int sq = 0; sq < DST / 4; sq++) {
        float4 av = ld4(Alog, (size_t)d * DST + sq * 4, f32);
        A[sq * 4 + 0] = -__expf(av.x); A[sq * 4 + 1] = -__expf(av.y);
        A[sq * 4 + 2] = -__expf(av.z); A[sq * 4 + 3] = -__expf(av.w);
    }
    __syncthreads();

    float P[DST], H[DST];
    #pragma unroll
    for (int s = 0; s < DST; s++) { P[s] = 1.f; H[s] = 0.f; }

    #pragma unroll 4
    for (int t = 0; t < TCH; t++) {
        const size_t off = (size_t)(row0 + t) * DIN + d;
        const float dtv = dt[off];
        const float xv  = ldf(x, off, f32);
        const float u   = dtv * xv;
        const float* bs = Bs + t * DST;
        #pragma unroll
        for (int s = 0; s < DST; s++) {
            const float e = __expf(dtv * A[s]);
            P[s] *= e;
            H[s] = e * H[s] + u * bs[s];
        }
    }

    const size_t base = (size_t)(b * NCH + c) * DST * DIN + d;
    #pragma unroll
    for (int s = 0; s < DST; s++) {
        Pb[base + (size_t)s * DIN] = P[s];
        Hb[base + (size_t)s * DIN] = H[s];
    }
}

// ---------------------------------------------------------------------------
// Kernel 5 (scan phase 2): cross-chunk exclusive scan per (b,s,d).
// IN-PLACE: Pb becomes hin[c] (state entering chunk c).
// ---------------------------------------------------------------------------
__global__ __launch_bounds__(256) void k_scan2(
    float* __restrict__ Pb,
    const float* __restrict__ Hb)
{
    const int idx = blockIdx.x * 256 + threadIdx.x;
    const int b   = idx / (DST * DIN);
    const int rem = idx % (DST * DIN);
    float h = 0.f;
    #pragma unroll 4
    for (int c = 0; c < NCH; c++) {
        const size_t o = (size_t)(b * NCH + c) * DST * DIN + rem;
        const float p = Pb[o], hb = Hb[o];
        Pb[o] = h;
        h = hb + p * h;
    }
}

// ---------------------------------------------------------------------------
// Kernel 6 (scan phase 3): local scan seeded with hin, emit y.
// ---------------------------------------------------------------------------
__global__ __launch_bounds__(256) void k_scan3(
    const void* __restrict__ x,
    const float* __restrict__ dt,
    const float* __restrict__ Bin,
    const float* __restrict__ Cin,
    const void* __restrict__ Alog,
    const void* __restrict__ Dv,
    const float* __restrict__ hin,   // = Pb after k_scan2
    const int*  __restrict__ flag,
    void* __restrict__ y)
{
    const bool f32 = (*flag != 0);
    __shared__ float Bs[TCH * DST];
    __shared__ float Cs[TCH * DST];
    const int tid = threadIdx.x;
    const int d = blockIdx.x * 256 + tid;
    const int c = blockIdx.y;
    const int b = blockIdx.z;
    const int row0 = b * LSEQ + c * TCH;

    if (tid < TCH * DST) {
        Bs[tid] = Bin[(size_t)row0 * DST + tid];
        Cs[tid] = Cin[(size_t)row0 * DST + tid];
    }

    float A[DST];
    #pragma unroll
    for (int sq = 0; sq < DST / 4; sq++) {
        float4 av = ld4(Alog, (size_t)d * DST + sq * 4, f32);
        A[sq * 4 + 0] = -__expf(av.x); A[sq * 4 + 1] = -__expf(av.y);
        A[sq * 4 + 2] = -__expf(av.z); A[sq * 4 + 3] = -__expf(av.w);
    }
    const float Dd = ldf(Dv, (size_t)d, f32);
    __syncthreads();

    float h[DST];
    const size_t base = (size_t)(b * NCH + c) * DST * DIN + d;
    #pragma unroll
    for (int s = 0; s < DST; s++) h[s] = hin[base + (size_t)s * DIN];

    #pragma unroll 4
    for (int t = 0; t < TCH; t++) {
        const size_t off = (size_t)(row0 + t) * DIN + d;
        const float dtv = dt[off];
        const float xv  = ldf(x, off, f32);
        const float u   = dtv * xv;
        const float* bs = Bs + t * DST;
        const float* cs = Cs + t * DST;
        float yv = Dd * xv;
        #pragma unroll
        for (int s = 0; s < DST; s++) {
            const float e = __expf(dtv * A[s]);
            h[s] = e * h[s] + u * bs[s];
            yv += h[s] * cs[s];
        }
        if (f32) ((float*)y)[off] = yv;
        else     ((__hip_bfloat16*)y)[off] = __float2bfloat16(yv);
    }
}

// ---------------------------------------------------------------------------
extern "C" void kernel_launch(void* const* d_in, const int* in_sizes, int n_in,
                              void* d_out, int out_size, void* d_ws, size_t ws_size,
                              hipStream_t stream) {
    const void* x    = d_in[0];
    const void* Wx   = d_in[1];
    const void* Wdt  = d_in[2];
    const void* bdt  = d_in[3];
    const void* Alog = d_in[4];
    const void* Dv   = d_in[5];

    // ---- workspace layout, NO aliasing (~77 MB; ws is >=268 MB) ----
    int*   flag  = (int*)d_ws;
    float* basep = (float*)d_ws + 16;
    float* drw   = basep;                                  // NROW*DTR   = 131072
    float* Bin   = drw + (size_t)NROW * DTR;               // NROW*DST   = 32768
    float* Cin   = Bin + (size_t)NROW * DST;               // NROW*DST   = 32768
    float* part  = Cin + (size_t)NROW * DST;               // KSP*NROW*96 = 6291456
    float* dt    = part + (size_t)KSP * NROW * KTOT;       // NROW*DIN   = 4194304
    float* Pb    = dt + (size_t)NROW * DIN;                // B*NCH*DST*DIN = 4194304
    float* Hb    = Pb + (size_t)B_SZ * NCH * DST * DIN;    // 4194304

    k_detect<<<1, 256, 0, stream>>>(x, flag);

    k_proj<<<dim3(NROW / 64, KSP), 192, 0, stream>>>(x, Wx, flag, part);

    k_comb<<<(NROW * KTOT) / 256, 256, 0, stream>>>(part, drw, Bin, Cin);

    k_dt<<<dim3(NROW / 64, DIN / 64), 256, 0, stream>>>(drw, Wdt, bdt, flag, dt);

    dim3 g1(DIN / 256, NCH, B_SZ);
    k_scan1<<<g1, 256, 0, stream>>>(x, dt, Bin, Alog, flag, Pb, Hb);

    k_scan2<<<(B_SZ * DST * DIN) / 256, 256, 0, stream>>>(Pb, Hb);

    k_scan3<<<g1, 256, 0, stream>>>(x, dt, Bin, Cin, Alog, Dv, Pb, flag, d_out);
}

// Round 6
// 176.201 us; speedup vs baseline: 5.1527x; 1.3198x over previous
//
#include <hip/hip_runtime.h>
#include <hip/hip_bf16.h>

// Problem constants
#define B_SZ 2
#define LSEQ 1024
#define DIN  2048
#define DST  16
#define DTR  64
#define KTOT 96              // DTR + 2*DST
#define NROW (B_SZ * LSEQ)   // 2048 (b,l) rows
#define NCH  64              // number of L-chunks
#define TCH  16              // timesteps per chunk (LSEQ / NCH)
#define KSP  32              // K-splits in k_proj (64 K each)

// bf16 (as ushort) -> float
__device__ __forceinline__ float b2f(unsigned int u) {
    union { unsigned int i; float f; } v;
    v.i = (u & 0xffffu) << 16;
    return v.f;
}

// scalar load: element i of a buffer that is either fp32 or bf16
__device__ __forceinline__ float ldf(const void* p, size_t i, bool f32) {
    return f32 ? ((const float*)p)[i] : b2f(((const unsigned short*)p)[i]);
}

// 4 consecutive elements as float4, dual dtype
__device__ __forceinline__ float4 ld4(const void* p, size_t i, bool f32) {
    if (f32) return *(const float4*)((const float*)p + i);
    const uint2 u = *(const uint2*)((const unsigned short*)p + i);
    float4 v;
    v.x = b2f(u.x); v.y = b2f(u.x >> 16);
    v.z = b2f(u.y); v.w = b2f(u.y >> 16);
    return v;
}

__device__ __forceinline__ float softplus_f(float v) {
    return (v > 20.f) ? v : log1pf(__expf(v));
}

// ---------------------------------------------------------------------------
// Kernel 0: dtype detector. flag=1 -> fp32, flag=0 -> bf16.
// ---------------------------------------------------------------------------
__global__ __launch_bounds__(256) void k_detect(const void* __restrict__ x,
                                                int* __restrict__ flag) {
    __shared__ int cnt;
    if (threadIdx.x == 0) cnt = 0;
    __syncthreads();
    const unsigned short* u = (const unsigned short*)x;
    int my = 0;
    for (int i = threadIdx.x; i < 4096; i += 256) {
        unsigned short v = u[2 * i];
        float af = fabsf(b2f(v));
        if (v == 0 || (af >= 6.0e-8f && af <= 1.7e7f)) my++;
    }
    atomicAdd(&cnt, my);
    __syncthreads();
    if (threadIdx.x == 0) *flag = (cnt < 2048) ? 1 : 0;
}

// ---------------------------------------------------------------------------
// Kernel 1: input projection, tiled split-K GEMM.
// C[2048][96] = x[2048][2048] . Wx^T. Tile 64 rows x 96 cols x 64 K.
// 256 threads (16 rt x 16 ct), thread-tile 4x6 (24 acc).
// __launch_bounds__(256,4): VGPR cap 128 — round-5 post-mortem: unbounded
// unroll ballooned this kernel to 256 VGPR + 83 MB scratch spills.
// ---------------------------------------------------------------------------
__global__ __launch_bounds__(256, 4) void k_proj(
    const void* __restrict__ x,      // [NROW][DIN]
    const void* __restrict__ Wx,     // [96][DIN]
    const int*  __restrict__ flag,
    float* __restrict__ part)        // [KSP][NROW][96]
{
    const bool f32 = (*flag != 0);
    __shared__ float lx[32][68];     // [k][row], padded
    __shared__ float lw[32][100];    // [k][col], padded
    const int tid = threadIdx.x;
    const int bx = blockIdx.x;       // row group (64 rows)
    const int by = blockIdx.y;       // K-split (64 K)
    const int rt = tid >> 4, ct = tid & 15;
    const int r0 = rt * 4, c0 = ct * 6;

    float acc[4][6];
    #pragma unroll
    for (int i = 0; i < 4; i++)
        #pragma unroll
        for (int k = 0; k < 6; k++) acc[i][k] = 0.f;

    for (int half = 0; half < 2; half++) {
        const int k0 = by * 64 + half * 32;
        // stage x tile: 64 rows x 32 k (K-major), 512 float4 / 256 threads
        #pragma unroll
        for (int it = 0; it < 2; it++) {
            const int idx = tid + it * 256;
            const int r = idx >> 3, q = idx & 7;
            float4 v = ld4(x, (size_t)(bx * 64 + r) * DIN + k0 + q * 4, f32);
            lx[q * 4 + 0][r] = v.x; lx[q * 4 + 1][r] = v.y;
            lx[q * 4 + 2][r] = v.z; lx[q * 4 + 3][r] = v.w;
        }
        // stage w tile: 96 cols x 32 k, 768 float4 / 256 threads
        #pragma unroll
        for (int it = 0; it < 3; it++) {
            const int idx = tid + it * 256;
            const int c = idx >> 3, q = idx & 7;
            float4 v = ld4(Wx, (size_t)c * DIN + k0 + q * 4, f32);
            lw[q * 4 + 0][c] = v.x; lw[q * 4 + 1][c] = v.y;
            lw[q * 4 + 2][c] = v.z; lw[q * 4 + 3][c] = v.w;
        }
        __syncthreads();

        #pragma unroll 4
        for (int j = 0; j < 32; j++) {
            const float4 xa = *(const float4*)&lx[j][r0];
            const float2 w0 = *(const float2*)&lw[j][c0];
            const float2 w1 = *(const float2*)&lw[j][c0 + 2];
            const float2 w2 = *(const float2*)&lw[j][c0 + 4];
            const float xr[4] = {xa.x, xa.y, xa.z, xa.w};
            const float wc[6] = {w0.x, w0.y, w1.x, w1.y, w2.x, w2.y};
            #pragma unroll
            for (int i = 0; i < 4; i++)
                #pragma unroll
                for (int k = 0; k < 6; k++)
                    acc[i][k] += xr[i] * wc[k];
        }
        __syncthreads();
    }

    float* p = part + ((size_t)by * NROW + bx * 64 + r0) * KTOT + c0;
    #pragma unroll
    for (int i = 0; i < 4; i++) {
        float* row = p + (size_t)i * KTOT;
        *(float2*)(row)     = make_float2(acc[i][0], acc[i][1]);
        *(float2*)(row + 2) = make_float2(acc[i][2], acc[i][3]);
        *(float2*)(row + 4) = make_float2(acc[i][4], acc[i][5]);
    }
}

// ---------------------------------------------------------------------------
// Kernel 2: combine K-split partials -> drw / Bin / Cin.
// ---------------------------------------------------------------------------
__global__ __launch_bounds__(256, 4) void k_comb(
    const float* __restrict__ part,
    float* __restrict__ drw, float* __restrict__ Bin, float* __restrict__ Cin)
{
    const int idx = blockIdx.x * 256 + threadIdx.x;   // < NROW*96
    float s = 0.f;
    #pragma unroll 8
    for (int ks = 0; ks < KSP; ks++)
        s += part[(size_t)ks * NROW * KTOT + idx];
    const int r = idx / KTOT, c = idx % KTOT;
    if (c < DTR)            drw[r * DTR + c] = s;
    else if (c < DTR + DST) Bin[r * DST + (c - DTR)] = s;
    else                    Cin[r * DST + (c - DTR - DST)] = s;
}

// ---------------------------------------------------------------------------
// Kernel 3: dt GEMM + softplus.  dt[r][d] = softplus(drw[r] . Wdt[d] + bdt[d])
// M=2048, N=2048, K=64 (single LDS stage). Block 256, tile 64x64, thread 4x4.
// ---------------------------------------------------------------------------
__global__ __launch_bounds__(256, 4) void k_dt(
    const float* __restrict__ drw,   // [NROW][DTR]
    const void* __restrict__ Wdt,    // [DIN][DTR]
    const void* __restrict__ bdt,    // [DIN]
    const int*  __restrict__ flag,
    float* __restrict__ dt)          // [NROW][DIN]
{
    const bool f32 = (*flag != 0);
    __shared__ float la[64][68];     // [k][row]
    __shared__ float lb[64][68];     // [k][col]
    const int tid = threadIdx.x;
    const int r0g = blockIdx.x * 64, c0g = blockIdx.y * 64;

    #pragma unroll
    for (int it = 0; it < 4; it++) {
        const int idx = tid + it * 256;
        const int r = idx >> 4, q = idx & 15;
        float4 v = *(const float4*)(drw + (size_t)(r0g + r) * DTR + q * 4);
        la[q * 4 + 0][r] = v.x; la[q * 4 + 1][r] = v.y;
        la[q * 4 + 2][r] = v.z; la[q * 4 + 3][r] = v.w;
    }
    #pragma unroll
    for (int it = 0; it < 4; it++) {
        const int idx = tid + it * 256;
        const int c = idx >> 4, q = idx & 15;
        float4 v = ld4(Wdt, (size_t)(c0g + c) * DTR + q * 4, f32);
        lb[q * 4 + 0][c] = v.x; lb[q * 4 + 1][c] = v.y;
        lb[q * 4 + 2][c] = v.z; lb[q * 4 + 3][c] = v.w;
    }
    __syncthreads();

    const int rt = tid >> 4, ct = tid & 15;
    const int r0 = rt * 4, c0 = ct * 4;
    float acc[4][4];
    #pragma unroll
    for (int i = 0; i < 4; i++)
        #pragma unroll
        for (int k = 0; k < 4; k++) acc[i][k] = 0.f;

    #pragma unroll 8
    for (int j = 0; j < 64; j++) {
        const float4 a = *(const float4*)&la[j][r0];
        const float4 b = *(const float4*)&lb[j][c0];
        const float ar[4] = {a.x, a.y, a.z, a.w};
        const float bc[4] = {b.x, b.y, b.z, b.w};
        #pragma unroll
        for (int i = 0; i < 4; i++)
            #pragma unroll
            for (int k = 0; k < 4; k++)
                acc[i][k] += ar[i] * bc[k];
    }

    float bd[4];
    #pragma unroll
    for (int k = 0; k < 4; k++) bd[k] = ldf(bdt, (size_t)(c0g + c0 + k), f32);
    #pragma unroll
    for (int i = 0; i < 4; i++) {
        float4 o;
        o.x = softplus_f(acc[i][0] + bd[0]);
        o.y = softplus_f(acc[i][1] + bd[1]);
        o.z = softplus_f(acc[i][2] + bd[2]);
        o.w = softplus_f(acc[i][3] + bd[3]);
        *(float4*)(dt + (size_t)(r0g + r0 + i) * DIN + c0g + c0) = o;
    }
}

// ---------------------------------------------------------------------------
// Kernel 4 (scan phase 1): per (b, chunk, d) chunk-local scan, h0=0.
//   P[s] = prod_t exp(dt*A[s]),  H[s] = end state.
// ---------------------------------------------------------------------------
__global__ __launch_bounds__(256, 4) void k_scan1(
    const void* __restrict__ x,
    const float* __restrict__ dt,
    const float* __restrict__ Bin,
    const void* __restrict__ Alog,
    const int*  __restrict__ flag,
    float* __restrict__ Pb,          // [B][NCH][DST][DIN]
    float* __restrict__ Hb)
{
    const bool f32 = (*flag != 0);
    __shared__ float Bs[TCH * DST];
    const int tid = threadIdx.x;
    const int d = blockIdx.x * 256 + tid;
    const int c = blockIdx.y;
    const int b = blockIdx.z;
    const int row0 = b * LSEQ + c * TCH;

    if (tid < TCH * DST) Bs[tid] = Bin[(size_t)row0 * DST + tid];

    float A[DST];
    #pragma unroll
    for (int sq = 0; sq < DST / 4; sq++) {
        float4 av = ld4(Alog, (size_t)d * DST + sq * 4, f32);
        A[sq * 4 + 0] = -__expf(av.x); A[sq * 4 + 1] = -__expf(av.y);
        A[sq * 4 + 2] = -__expf(av.z); A[sq * 4 + 3] = -__expf(av.w);
    }
    __syncthreads();

    float P[DST], H[DST];
    #pragma unroll
    for (int s = 0; s < DST; s++) { P[s] = 1.f; H[s] = 0.f; }

    #pragma unroll 4
    for (int t = 0; t < TCH; t++) {
        const size_t off = (size_t)(row0 + t) * DIN + d;
        const float dtv = dt[off];
        const float xv  = ldf(x, off, f32);
        const float u   = dtv * xv;
        const float* bs = Bs + t * DST;
        #pragma unroll
        for (int s = 0; s < DST; s++) {
            const float e = __expf(dtv * A[s]);
            P[s] *= e;
            H[s] = e * H[s] + u * bs[s];
        }
    }

    const size_t base = (size_t)(b * NCH + c) * DST * DIN + d;
    #pragma unroll
    for (int s = 0; s < DST; s++) {
        Pb[base + (size_t)s * DIN] = P[s];
        Hb[base + (size_t)s * DIN] = H[s];
    }
}

// ---------------------------------------------------------------------------
// Kernel 5 (scan phase 2): cross-chunk exclusive scan per (b,s,d).
// IN-PLACE: Pb becomes hin[c] (state entering chunk c).
// ---------------------------------------------------------------------------
__global__ __launch_bounds__(256, 4) void k_scan2(
    float* __restrict__ Pb,
    const float* __restrict__ Hb)
{
    const int idx = blockIdx.x * 256 + threadIdx.x;
    const int b   = idx / (DST * DIN);
    const int rem = idx % (DST * DIN);
    float h = 0.f;
    #pragma unroll 4
    for (int c = 0; c < NCH; c++) {
        const size_t o = (size_t)(b * NCH + c) * DST * DIN + rem;
        const float p = Pb[o], hb = Hb[o];
        Pb[o] = h;
        h = hb + p * h;
    }
}

// ---------------------------------------------------------------------------
// Kernel 6 (scan phase 3): local scan seeded with hin, emit y.
// ---------------------------------------------------------------------------
__global__ __launch_bounds__(256, 4) void k_scan3(
    const void* __restrict__ x,
    const float* __restrict__ dt,
    const float* __restrict__ Bin,
    const float* __restrict__ Cin,
    const void* __restrict__ Alog,
    const void* __restrict__ Dv,
    const float* __restrict__ hin,   // = Pb after k_scan2
    const int*  __restrict__ flag,
    void* __restrict__ y)
{
    const bool f32 = (*flag != 0);
    __shared__ float Bs[TCH * DST];
    __shared__ float Cs[TCH * DST];
    const int tid = threadIdx.x;
    const int d = blockIdx.x * 256 + tid;
    const int c = blockIdx.y;
    const int b = blockIdx.z;
    const int row0 = b * LSEQ + c * TCH;

    if (tid < TCH * DST) {
        Bs[tid] = Bin[(size_t)row0 * DST + tid];
        Cs[tid] = Cin[(size_t)row0 * DST + tid];
    }

    float A[DST];
    #pragma unroll
    for (int sq = 0; sq < DST / 4; sq++) {
        float4 av = ld4(Alog, (size_t)d * DST + sq * 4, f32);
        A[sq * 4 + 0] = -__expf(av.x); A[sq * 4 + 1] = -__expf(av.y);
        A[sq * 4 + 2] = -__expf(av.z); A[sq * 4 + 3] = -__expf(av.w);
    }
    const float Dd = ldf(Dv, (size_t)d, f32);
    __syncthreads();

    float h[DST];
    const size_t base = (size_t)(b * NCH + c) * DST * DIN + d;
    #pragma unroll
    for (int s = 0; s < DST; s++) h[s] = hin[base + (size_t)s * DIN];

    #pragma unroll 4
    for (int t = 0; t < TCH; t++) {
        const size_t off = (size_t)(row0 + t) * DIN + d;
        const float dtv = dt[off];
        const float xv  = ldf(x, off, f32);
        const float u   = dtv * xv;
        const float* bs = Bs + t * DST;
        const float* cs = Cs + t * DST;
        float yv = Dd * xv;
        #pragma unroll
        for (int s = 0; s < DST; s++) {
            const float e = __expf(dtv * A[s]);
            h[s] = e * h[s] + u * bs[s];
            yv += h[s] * cs[s];
        }
        if (f32) ((float*)y)[off] = yv;
        else     ((__hip_bfloat16*)y)[off] = __float2bfloat16(yv);
    }
}

// ---------------------------------------------------------------------------
extern "C" void kernel_launch(void* const* d_in, const int* in_sizes, int n_in,
                              void* d_out, int out_size, void* d_ws, size_t ws_size,
                              hipStream_t stream) {
    const void* x    = d_in[0];
    const void* Wx   = d_in[1];
    const void* Wdt  = d_in[2];
    const void* bdt  = d_in[3];
    const void* Alog = d_in[4];
    const void* Dv   = d_in[5];

    // ---- workspace layout, NO aliasing (~77 MB; ws is >=268 MB) ----
    int*   flag  = (int*)d_ws;
    float* basep = (float*)d_ws + 16;
    float* drw   = basep;                                  // NROW*DTR   = 131072
    float* Bin   = drw + (size_t)NROW * DTR;               // NROW*DST   = 32768
    float* Cin   = Bin + (size_t)NROW * DST;               // NROW*DST   = 32768
    float* part  = Cin + (size_t)NROW * DST;               // KSP*NROW*96 = 6291456
    float* dt    = part + (size_t)KSP * NROW * KTOT;       // NROW*DIN   = 4194304
    float* Pb    = dt + (size_t)NROW * DIN;                // B*NCH*DST*DIN = 4194304
    float* Hb    = Pb + (size_t)B_SZ * NCH * DST * DIN;    // 4194304

    k_detect<<<1, 256, 0, stream>>>(x, flag);

    k_proj<<<dim3(NROW / 64, KSP), 256, 0, stream>>>(x, Wx, flag, part);

    k_comb<<<(NROW * KTOT) / 256, 256, 0, stream>>>(part, drw, Bin, Cin);

    k_dt<<<dim3(NROW / 64, DIN / 64), 256, 0, stream>>>(drw, Wdt, bdt, flag, dt);

    dim3 g1(DIN / 256, NCH, B_SZ);
    k_scan1<<<g1, 256, 0, stream>>>(x, dt, Bin, Alog, flag, Pb, Hb);

    k_scan2<<<(B_SZ * DST * DIN) / 256, 256, 0, stream>>>(Pb, Hb);

    k_scan3<<<g1, 256, 0, stream>>>(x, dt, Bin, Cin, Alog, Dv, Pb, flag, d_out);
}